// Round 14
// baseline (343.875 us; speedup 1.0000x reference)
//
#include <hip/hip_runtime.h>
#include <hip/hip_bf16.h>
#include <hip/hip_cooperative_groups.h>
#include <cstdint>
#include <cstddef>

namespace cg = cooperative_groups;

// ---------- types ----------
typedef _Float16 f16x8 __attribute__((ext_vector_type(8)));
typedef float    f32x4 __attribute__((ext_vector_type(4)));

#define VOC    50000
// tree (symmetric-folded): K = 36 blocks * 64 + 128 concat = 2432 = 19 stages
#define W2T    2432
#define NSTG_T 19
// final (asymmetric kron): K = 4096 + 128 = 4224 = 33 stages
#define W2F    4224
#define NSTG_F 33
#define STG    8192      // elems per 128-k stage (128 k x 64 n) = 16 KB
#define XSTR   72        // LDS row stride in f16 elems (144 B, 16B-aligned)
#define TPW    8         // trees per WG (512 thr, 1 WG/CU)
#define IPW    16        // items per final-WG

// ---------- static device scratch ----------
__device__ __attribute__((aligned(256))) unsigned short g_vocT[(size_t)VOC * 64];   // f16
__device__ __attribute__((aligned(256))) unsigned short g_roots[2048 * 64];         // f16
// weights (f16) in stage-fragment order:
//   d = s*8192 + kbl*2048 + nt*512 + q*128 + sub*8 + z
//   n = nt*16 + sub, k = s*128 + kbl*32 + q*8 + z
// g_cpstU kron part (k < 2304): block b = k>>6 (nested bi<=bj enumeration),
//   slot holds Wfold[n][i,j], i = bi*8+z (A-vector), j = bj*8+2q+p2 (A-scalar,
//   pair-adjacent -> one b32 read).  Wfold = W[i,j]+W[j,i] (bi<bj) else W[i,j].
// k >= 2304 -> concat (cps_w).
__device__ __attribute__((aligned(256))) unsigned short g_cpstU[(size_t)NSTG_T * STG];
__device__ __attribute__((aligned(256))) unsigned short g_cprtU[(size_t)NSTG_F * STG];
__device__ float g_smw[7 * 64];
__device__ float g_smb[7];
__device__ float g_biasC[64];   // cps_b + cpst_b
__device__ float g_biasF[64];   // cpr_b + cprt_b

// per-stage kron block params, packed: half0 bits[0:6], half1 bits[7:13]
#define KE(BI0,BJ0,R0,BI1,BJ1,R1) \
    ((BI0) | ((BJ0) << 3) | ((R0) << 6) | ((BI1) << 7) | ((BJ1) << 10) | ((R1) << 13))
__device__ __constant__ int g_ktab[18] = {
    KE(0,0,1, 0,1,1), KE(0,2,0, 0,3,0), KE(0,4,0, 0,5,0), KE(0,6,0, 0,7,0),
    KE(1,1,1, 1,2,1), KE(1,3,0, 1,4,0), KE(1,5,0, 1,6,0), KE(1,7,0, 2,2,1),
    KE(2,3,1, 2,4,0), KE(2,5,0, 2,6,0), KE(2,7,0, 3,3,1), KE(3,4,1, 3,5,0),
    KE(3,6,0, 3,7,0), KE(4,4,1, 4,5,1), KE(4,6,0, 4,7,0), KE(5,5,1, 5,6,1),
    KE(5,7,0, 6,6,1), KE(6,7,1, 7,7,1)
};

__device__ __forceinline__ float b2f(unsigned short u) {
    unsigned int x = ((unsigned int)u) << 16;
    return __builtin_bit_cast(float, x);
}
__device__ __forceinline__ unsigned short f2b(float f) {
    return __builtin_bit_cast(unsigned short, (__bf16)f);
}
__device__ __forceinline__ unsigned short f2h(float f) {
    return __builtin_bit_cast(unsigned short, (_Float16)f);
}
__device__ __forceinline__ float scrub(float v) {
    return fminf(fmaxf(v, -64.f), 64.f);
}
__device__ __forceinline__ float ldf(const void* p, size_t i, int isb) {
    return isb ? b2f(((const unsigned short*)p)[i]) : ((const float*)p)[i];
}
__device__ __forceinline__ int detect_isb(const void* voc_b) {
    const unsigned int* p = (const unsigned int*)voc_b;
    int ok = 1;
    for (int k = 0; k < 32; k++) {
        float v = b2f((unsigned short)(p[k] & 0xFFFFu));
        if (!(fabsf(v) <= 0.0502f)) ok = 0;
    }
    return ok;
}

// epilogue for owned chunk CO: add bias, tanh, store (f16)
#define EPILOGUE(CO)                                                          \
    if (lv < 5) {                                                             \
        _Pragma("unroll")                                                     \
        for (int nt = 0; nt < 4; nt++) {                                      \
            int e = nt * 16 + sub;                                            \
            _Pragma("unroll")                                                 \
            for (int rr = 0; rr < 4; rr++) {                                  \
                int m = chv[CO] * 16 + q * 4 + rr;                            \
                if (m < nodes) {                                              \
                    int t2 = m >> lg, n2 = m & (cnew - 1);                    \
                    Xs[(t2 * 64 + n2) * XSTR + e] =                           \
                        f2h(tanhf(scrub(acc[CO][nt][rr] + biasC[e])));        \
                }                                                             \
            }                                                                 \
        }                                                                     \
    } else {                                                                  \
        _Pragma("unroll")                                                     \
        for (int nt = 0; nt < 4; nt++) {                                      \
            int e = nt * 16 + sub;                                            \
            _Pragma("unroll")                                                 \
            for (int rr = 0; rr < 4; rr++) {                                  \
                int m = q * 4 + rr;                                           \
                if (m < TPW)                                                  \
                    g_roots[((size_t)wg * TPW + m) * 64 + e] =                \
                        f2h(tanhf(scrub(acc[CO][nt][rr] + biasC[e])));        \
            }                                                                 \
        }                                                                     \
    }

// pair exchange: wave-indexed 8-slot scratch (receiver reads wave^1)
#define EXSEND(CS)                                                            \
    { _Pragma("unroll")                                                       \
      for (int nt = 0; nt < 4; nt++)                                          \
          *(f32x4*)(exchS + wave * 1024 + nt * 256 + lane * 4) = acc[CS][nt]; }

#define EXRECV(CO)                                                            \
    { _Pragma("unroll")                                                       \
      for (int nt = 0; nt < 4; nt++) {                                        \
          f32x4 v_ = *(const f32x4*)(exchS + (wave ^ 1) * 1024 + nt * 256 + lane * 4); \
          _Pragma("unroll")                                                   \
          for (int z = 0; z < 4; z++) acc[CO][nt][z] += v_[z];                \
      } }

// load this wave's 8 B-fragments of a stage from GLOBAL (L1/L2-resident)
#define BLD8(BF, SBASE)                                                       \
    { const unsigned short* gs_ = (SBASE) + half * 4096 + lane * 8;           \
      _Pragma("unroll")                                                       \
      for (int j = 0; j < 8; j++)                                             \
          BF[j] = *(const f16x8*)(gs_ + (j >> 2) * 2048 + (j & 3) * 512); }

#define KMM(CI, AV, B0, B1, B2, B3)                                           \
    { f16x8 a_ = (AV);                                                        \
      acc[CI][0] = __builtin_amdgcn_mfma_f32_16x16x32_f16(a_, B0, acc[CI][0], 0, 0, 0); \
      acc[CI][1] = __builtin_amdgcn_mfma_f32_16x16x32_f16(a_, B1, acc[CI][1], 0, 0, 0); \
      acc[CI][2] = __builtin_amdgcn_mfma_f32_16x16x32_f16(a_, B2, acc[CI][2], 0, 0, 0); \
      acc[CI][3] = __builtin_amdgcn_mfma_f32_16x16x32_f16(a_, B3, acc[CI][3], 0, 0, 0); }

#define KBLOCKR(BF, BI, BJ, RLD)                                              \
    if (act[0]) {                                                             \
        if (RLD) {                                                            \
            lA0 = *(const f16x8*)(Xs + slotL[0] + (BI) * 8);                  \
            if (act[1]) lA1 = *(const f16x8*)(Xs + slotL[1] + (BI) * 8);      \
            if (act[2]) lA2 = *(const f16x8*)(Xs + slotL[2] + (BI) * 8);      \
            if (act[3]) lA3 = *(const f16x8*)(Xs + slotL[3] + (BI) * 8);      \
        }                                                                     \
        _Float16 sc0[4], sc1[4];                                              \
        _Pragma("unroll")                                                     \
        for (int c = 0; c < 4; c++)                                           \
            if (act[c]) {                                                     \
                unsigned pr_ = *(const unsigned*)(Xs + slotL[c] + (BJ) * 8 + 2 * q); \
                sc0[c] = __builtin_bit_cast(_Float16, (unsigned short)(pr_ & 0xFFFFu)); \
                sc1[c] = __builtin_bit_cast(_Float16, (unsigned short)(pr_ >> 16));     \
            }                                                                 \
        _Pragma("unroll")                                                     \
        for (int p2 = 0; p2 < 2; p2++) {                                      \
            KMM(0, lA0 * (p2 ? sc1[0] : sc0[0]),                              \
                BF[p2 * 4 + 0], BF[p2 * 4 + 1], BF[p2 * 4 + 2], BF[p2 * 4 + 3]) \
            if (act[1]) KMM(1, lA1 * (p2 ? sc1[1] : sc0[1]),                  \
                BF[p2 * 4 + 0], BF[p2 * 4 + 1], BF[p2 * 4 + 2], BF[p2 * 4 + 3]) \
            if (act[2]) KMM(2, lA2 * (p2 ? sc1[2] : sc0[2]),                  \
                BF[p2 * 4 + 0], BF[p2 * 4 + 1], BF[p2 * 4 + 2], BF[p2 * 4 + 3]) \
            if (act[3]) KMM(3, lA3 * (p2 ? sc1[3] : sc0[3]),                  \
                BF[p2 * 4 + 0], BF[p2 * 4 + 1], BF[p2 * 4 + 2], BF[p2 * 4 + 3]) \
        }                                                                     \
    }

#define KRUNR(S, BF)                                                          \
    {                                                                         \
        int e_   = g_ktab[S];                                                 \
        int ent_ = half ? (e_ >> 7) : e_;                                     \
        int bi_  = ent_ & 7;                                                  \
        int bj_  = (ent_ >> 3) & 7;                                           \
        int rld_ = (ent_ >> 6) & 1;                                           \
        KBLOCKR((BF), bi_, bj_, rld_)                                         \
    }

// final: load wave w's 4 B-fragments of stage S from GLOBAL
#define BLD4(BF, S)                                                           \
    { const unsigned short* gs_ = g_cprtU + (size_t)(S) * STG + w * 512 + lane * 8; \
      _Pragma("unroll")                                                       \
      for (int j = 0; j < 4; j++)                                             \
          BF[j] = *(const f16x8*)(gs_ + j * 2048); }

#define FKRONR(S, BF)                                                         \
    { _Pragma("unroll")                                                       \
      for (int ii = 0; ii < 2; ii++) {                                        \
          int i_ = 2 * (S) + ii;                                              \
          _Float16 li_ = __builtin_bit_cast(_Float16, Lv[rowLo + i_]);        \
          _Pragma("unroll")                                                   \
          for (int p2 = 0; p2 < 2; p2++) {                                    \
              f16x8 afr_ = Ra[p2] * li_;                                      \
              accF = __builtin_amdgcn_mfma_f32_16x16x32_f16(afr_, BF[2 * ii + p2], accF, 0, 0, 0); \
          }                                                                   \
      } }

// ---------- SINGLE cooperative kernel: prep -> tree -> final ----------
// 256 WGs x 512 thr, 1 WG/CU (LDS 106752 B) -> all co-resident; grid.sync()
// between phases replaces 2 kernel-boundary drains (~25-30us each, the
// quasi-constant ~95us residual rounds 0-13 never touched).
// Phase 2 is round-13's k_tree verbatim (barrier-free register-B streaming).
// Phase 1/3 LDS aliases into Xs/exchS.
__global__ __launch_bounds__(512, 2)
void k_all(const int* __restrict__ lleaf, const int* __restrict__ rleaf,
           const void* __restrict__ voc_w, const void* __restrict__ voc_b,
           const void* cps_w, const void* cps_b, const void* cpst_w, const void* cpst_b,
           const void* cpr_w, const void* cpr_b, const void* cprt_w, const void* cprt_b,
           const void* sm_w, const void* sm_b, void* __restrict__ out)
{
    __shared__ __attribute__((aligned(16))) unsigned short Xs[512 * XSTR];   // 73728 B
    __shared__ __attribute__((aligned(16))) float exchS[8192];               // 32768 B
    __shared__ float biasC[64];
    const int tid = threadIdx.x;
    const int wg  = blockIdx.x;
    const int isb = detect_isb(voc_b);
    cg::grid_group grid = cg::this_grid();

    // ===================== PHASE 1: weight prep + vocT =====================
    {
        int gid = wg * 512 + tid;
        const int stride = 256 * 512;
        // g_cpstU: symmetric-folded kron (role-swapped, pair-adjacent) + concat
        for (int d = gid; d < 64 * W2T; d += stride) {
            int s    = d / STG;
            int rem  = d - s * STG;
            int kbl  = rem >> 11;
            int rem2 = rem & 2047;
            int nt   = rem2 >> 9;
            int rem3 = rem2 & 511;
            int q    = rem3 >> 7;
            int rem4 = rem3 & 127;
            int sub  = rem4 >> 3;
            int z    = rem4 & 7;
            int n    = nt * 16 + sub;
            int k    = s * 128 + kbl * 32 + q * 8 + z;
            float w;
            if (k < 2304) {
                int b   = k >> 6;
                int p2l = (k >> 5) & 1;
                int bi = 0, remb = b;
                while (remb >= 8 - bi) { remb -= 8 - bi; bi++; }
                int bj = bi + remb;
                int i = bi * 8 + z;
                int j = bj * 8 + 2 * q + p2l;
                w = ldf(cpst_w, (size_t)n * 4096 + i * 64 + j, isb);
                if (bi != bj)
                    w += ldf(cpst_w, (size_t)n * 4096 + j * 64 + i, isb);
            } else {
                w = ldf(cps_w, (size_t)n * 128 + (k - 2304), isb);
            }
            g_cpstU[d] = f2h(w);
        }
        // g_cprtU: plain layout (33 stages)
        for (int d = gid; d < 64 * W2F; d += stride) {
            int s    = d / STG;
            int rem  = d - s * STG;
            int kbl  = rem >> 11;
            int rem2 = rem & 2047;
            int nt   = rem2 >> 9;
            int rem3 = rem2 & 511;
            int q    = rem3 >> 7;
            int rem4 = rem3 & 127;
            int sub  = rem4 >> 3;
            int z    = rem4 & 7;
            int n    = nt * 16 + sub;
            int k    = s * 128 + kbl * 32 + q * 8 + z;
            float v2 = (k < 4096) ? ldf(cprt_w, (size_t)n * 4096 + k, isb)
                                  : ldf(cpr_w,  (size_t)n * 128 + (k - 4096), isb);
            g_cprtU[d] = f2h(v2);
        }
        for (int i = gid; i < 448; i += stride) g_smw[i] = ldf(sm_w, i, isb);
        if (gid < 64) {
            g_biasC[gid] = ldf(cps_b, gid, isb) + ldf(cpst_b, gid, isb);
            g_biasF[gid] = ldf(cpr_b, gid, isb) + ldf(cprt_b, gid, isb);
        }
        if (gid < 7) g_smb[gid] = ldf(sm_b, gid, isb);

        // vocT: voc_w (64 x 50000) -> g_vocT[50000][64] f16, fold voc_b
        float* tileF = (float*)Xs;               // [64][65]
        float* vbF   = exchS;                    // [64]
        if (tid < 64) vbF[tid] = ldf(voc_b, tid, isb);
        __syncthreads();
        for (int vt = wg; vt < (VOC + 63) / 64; vt += 256) {
            int v0 = vt * 64;
            int vl = tid & 63, dr = tid >> 6;    // dr 0..7
            #pragma unroll
            for (int i = 0; i < 8; i++) {
                int d = dr * 8 + i;
                int v = v0 + vl;
                tileF[vl * 65 + d] = (v < VOC) ? ldf(voc_w, (size_t)d * VOC + v, isb) : 0.f;
            }
            __syncthreads();
            int dl = tid & 63, vr0 = tid >> 6;
            #pragma unroll
            for (int i = 0; i < 8; i++) {
                int vr = vr0 * 8 + i;
                int v = v0 + vr;
                if (v < VOC) g_vocT[(size_t)v * 64 + dl] = f2h(tileF[vr * 65 + dl] + vbF[dl]);
            }
            __syncthreads();
        }
    }
    __threadfence();
    grid.sync();

    // ===================== PHASE 2: tree composition =====================
    if (tid < 64) biasC[tid] = g_biasC[tid];
    {
        int t = tid >> 6, i = tid & 63;
        int gidx = wg * TPW + t;                 // 0..1023 left, 1024..2047 right
        int b = (gidx < 1024) ? gidx : gidx - 1024;
        const int* lv2 = (gidx < 1024) ? lleaf : rleaf;
        int idx = lv2[b * 64 + i];
        idx = (idx < 0) ? 0 : ((idx >= VOC) ? VOC - 1 : idx);
        const uint4* src = (const uint4*)(g_vocT + (size_t)idx * 64);
        uint4* dst = (uint4*)(Xs + tid * XSTR);
        #pragma unroll
        for (int z = 0; z < 8; z++) dst[z] = src[z];
    }
    __syncthreads();   // Xs + biasC ready

    {
        const int lane = tid & 63, wave = tid >> 6;
        const int q = lane >> 4, sub = lane & 15;
        const int p = wave >> 1, half = wave & 1;

        #pragma unroll 1
        for (int lv = 0; lv < 6; lv++) {
            const int lg = 5 - lv;
            const int cnew = 1 << lg;
            const int nodes = TPW << lg;             // 256,128,64,32,16,8
            const int nchunks = (nodes + 15) >> 4;   // 16,8,4,2,1,1

            int act[4], chv[4], slotL[4];
            #pragma unroll
            for (int c = 0; c < 4; c++) {
                int ch = p + 4 * c;                  // spread: all pairs active
                act[c] = (ch < nchunks);
                chv[c] = ch;
                int m = ch * 16 + sub;
                if (!act[c] || m >= nodes) m = 0;
                int t = m >> lg, n = m & (cnew - 1);
                slotL[c] = (t * 64 + 2 * n) * XSTR;
            }

            f16x8 lA0 = {}, lA1 = {}, lA2 = {}, lA3 = {};
            f32x4 acc[4][4];
            #pragma unroll
            for (int c = 0; c < 4; c++)
                #pragma unroll
                for (int nt = 0; nt < 4; nt++)
                    #pragma unroll
                    for (int z = 0; z < 4; z++) acc[c][nt][z] = 0.f;

            // 18 kron stages + concat, ping-pong register B, NO barriers
            f16x8 bfA[8], bfB[8];
            if (act[0]) BLD8(bfA, g_cpstU)
            #pragma unroll 1
            for (int t = 0; t < 9; t++) {
                if (act[0]) BLD8(bfB, g_cpstU + (size_t)(2 * t + 1) * STG)
                KRUNR(2 * t, bfA)
                if (act[0]) BLD8(bfA, g_cpstU + (size_t)(2 * t + 2) * STG)
                KRUNR(2 * t + 1, bfB)
            }
            if (act[0]) {                            // concat (bfA = stage 18)
                #pragma unroll
                for (int p2 = 0; p2 < 2; p2++) {
                    #pragma unroll
                    for (int c = 0; c < 4; c++) {
                        if (!act[c]) continue;
                        f16x8 A = *(const f16x8*)(Xs + slotL[c] + half * XSTR + p2 * 32 + q * 8);
                        acc[c][0] = __builtin_amdgcn_mfma_f32_16x16x32_f16(A, bfA[p2 * 4 + 0], acc[c][0], 0, 0, 0);
                        acc[c][1] = __builtin_amdgcn_mfma_f32_16x16x32_f16(A, bfA[p2 * 4 + 1], acc[c][1], 0, 0, 0);
                        acc[c][2] = __builtin_amdgcn_mfma_f32_16x16x32_f16(A, bfA[p2 * 4 + 2], acc[c][2], 0, 0, 0);
                        acc[c][3] = __builtin_amdgcn_mfma_f32_16x16x32_f16(A, bfA[p2 * 4 + 3], acc[c][3], 0, 0, 0);
                    }
                }
            }

            // pair exchange + epilogue (first barrier also orders Xs reads)
            if (half == 0) { if (act[1]) EXSEND(1) } else { if (act[0]) EXSEND(0) }
            __syncthreads();
            if (half == 0) {
                if (act[0]) { EXRECV(0) EPILOGUE(0) }
            } else {
                if (act[1]) { EXRECV(1) EPILOGUE(1) }
            }
            __syncthreads();
            if (half == 0) { if (act[3]) EXSEND(3) } else { if (act[2]) EXSEND(2) }
            __syncthreads();
            if (half == 0) {
                if (act[2]) { EXRECV(2) EPILOGUE(2) }
            } else {
                if (act[3]) { EXRECV(3) EPILOGUE(3) }
            }
            __syncthreads();
        }
    }
    __threadfence();
    grid.sync();

    // ===================== PHASE 3: final + softmax (blocks 0..63) =====================
    if (wg < 64) {
        unsigned short* Lv = Xs;                     // IPW*XSTR
        unsigned short* Rv = Xs + IPW * XSTR;
        float* actS  = exchS;                        // [16][65] flat
        float* smwS  = exchS + 1040;                 // [7][64] flat
        float* smbS  = exchS + 1488;                 // [7]
        float* biasF = exchS + 1496;                 // [64]

        if (tid < 64) biasF[tid] = g_biasF[tid];
        if (tid < 7)  smbS[tid] = g_smb[tid];
        for (int z = tid; z < 448; z += 512) smwS[z] = g_smw[z];
        if (tid < 256) {
            int side = tid >> 7, idx = tid & 127;
            int item = idx >> 3, piece = idx & 7;
            const uint4* s4 = (const uint4*)(g_roots +
                ((size_t)(side * 1024) + (size_t)wg * IPW + item) * 64 + piece * 8);
            uint4* d4 = (uint4*)((side ? Rv : Lv) + item * XSTR + piece * 8);
            *d4 = *s4;
        }
        __syncthreads();

        if (tid < 256) {
            const int lane = tid & 63, w = tid >> 6;
            const int q = lane >> 4, sub = lane & 15;
            const int rowLo = sub * XSTR;

            f16x8 bA[4], bB[4];
            BLD4(bA, 0)
            f16x8 Ra[2];
            Ra[0] = *(const f16x8*)(Rv + rowLo + q * 8);
            Ra[1] = *(const f16x8*)(Rv + rowLo + 32 + q * 8);
            f32x4 accF = {0.f, 0.f, 0.f, 0.f};

            #pragma unroll 1
            for (int t = 0; t < 16; t++) {           // kron stages 0..31
                BLD4(bB, 2 * t + 1)
                FKRONR(2 * t, bA)
                BLD4(bA, 2 * t + 2)                  // t=15 -> stage 32 (concat)
                FKRONR(2 * t + 1, bB)
            }
            {   // concat stage (bA = stage 32, kbl = j)
                f16x8 A4[4];
                A4[0] = *(const f16x8*)(Lv + rowLo + q * 8);
                A4[1] = *(const f16x8*)(Lv + rowLo + 32 + q * 8);
                A4[2] = *(const f16x8*)(Rv + rowLo + q * 8);
                A4[3] = *(const f16x8*)(Rv + rowLo + 32 + q * 8);
                #pragma unroll
                for (int kbl = 0; kbl < 4; kbl++)
                    accF = __builtin_amdgcn_mfma_f32_16x16x32_f16(A4[kbl], bA[kbl], accF, 0, 0, 0);
            }
            // epilogue: bias + leaky_relu -> LDS
            int e = w * 16 + sub;
            #pragma unroll
            for (int rr = 0; rr < 4; rr++) {
                int item = q * 4 + rr;
                float v = scrub(accF[rr] + biasF[e]);
                v = (v > 0.f) ? v : 0.01f * v;
                actS[item * 65 + e] = v;
            }
        }
        __syncthreads();

        if (tid < IPW) {
            float lg[7];
            #pragma unroll
            for (int j = 0; j < 7; j++) lg[j] = smbS[j];
            for (int e = 0; e < 64; e++) {
                float a = actS[tid * 65 + e];
                #pragma unroll
                for (int j = 0; j < 7; j++) lg[j] += smwS[j * 64 + e] * a;
            }
            float mx = lg[0];
            #pragma unroll
            for (int j = 1; j < 7; j++) mx = fmaxf(mx, lg[j]);
            float s = 0.f, pr[7];
            #pragma unroll
            for (int j = 0; j < 7; j++) { pr[j] = expf(lg[j] - mx); s += pr[j]; }
            float inv = 1.f / s;
            size_t b = (size_t)wg * IPW + tid;
            if (isb) {
                unsigned short* o = (unsigned short*)out;
                #pragma unroll
                for (int j = 0; j < 7; j++) o[b * 7 + j] = f2b(pr[j] * inv);
            } else {
                float* o = (float*)out;
                #pragma unroll
                for (int j = 0; j < 7; j++) o[b * 7 + j] = pr[j] * inv;
            }
        }
    }
}

// ---------- host launcher ----------
extern "C" void kernel_launch(void* const* d_in, const int* in_sizes, int n_in,
                              void* d_out, int out_size, void* d_ws, size_t ws_size,
                              hipStream_t stream) {
    const int* lleaf = (const int*)d_in[0];
    const int* rleaf = (const int*)d_in[1];
    const void* voc_w  = d_in[2];
    const void* voc_b  = d_in[3];
    const void* cps_w  = d_in[4];
    const void* cps_b  = d_in[5];
    const void* cpst_w = d_in[6];
    const void* cpst_b = d_in[7];
    const void* cpr_w  = d_in[8];
    const void* cpr_b  = d_in[9];
    const void* cprt_w = d_in[10];
    const void* cprt_b = d_in[11];
    const void* sm_w   = d_in[12];
    const void* sm_b   = d_in[13];
    void* out = d_out;

    void* args[] = {
        (void*)&lleaf, (void*)&rleaf, (void*)&voc_w, (void*)&voc_b,
        (void*)&cps_w, (void*)&cps_b, (void*)&cpst_w, (void*)&cpst_b,
        (void*)&cpr_w, (void*)&cpr_b, (void*)&cprt_w, (void*)&cprt_b,
        (void*)&sm_w, (void*)&sm_b, (void*)&out
    };
    hipLaunchCooperativeKernel(k_all, dim3(256), dim3(512), args, 0, stream);
}

// Round 15
// 165.096 us; speedup vs baseline: 2.0829x; 2.0829x over previous
//
#include <hip/hip_runtime.h>
#include <hip/hip_bf16.h>
#include <cstdint>
#include <cstddef>

// ---------- types ----------
typedef _Float16 f16x8 __attribute__((ext_vector_type(8)));
typedef float    f32x4 __attribute__((ext_vector_type(4)));

#define VOC    50000
// k_tree (symmetric-folded): K = 36 blocks * 64 + 128 concat = 2432 = 19 stages
#define W2T    2432
#define NSTG_T 19
// k_final (asymmetric kron): K = 4096 + 128 = 4224 = 33 stages
#define W2F    4224
#define NSTG_F 33
#define STG    8192      // elems per 128-k stage (128 k x 64 n) = 16 KB
#define XSTR   72        // LDS row stride in f16 elems (144 B, 16B-aligned)
#define TPW    8         // trees per WG in k_tree (512 thr, 1 WG/CU)
#define IPW    16        // items per WG in k_final

// ---------- static device scratch ----------
__device__ __attribute__((aligned(256))) unsigned short g_vocT[(size_t)VOC * 64];   // f16
__device__ __attribute__((aligned(256))) unsigned short g_roots[2048 * 64];         // f16
// weights (f16) in stage-fragment order:
//   d = s*8192 + kbl*2048 + nt*512 + q*128 + sub*8 + z
//   n = nt*16 + sub, k = s*128 + kbl*32 + q*8 + z
// g_cpstU kron part (k < 2304): block b = k>>6 (nested bi<=bj enumeration),
//   slot holds Wfold[n][i,j], i = bi*8+z (A-vector), j = bj*8+2q+p2 (A-scalar,
//   pair-adjacent -> one b32 read).  Wfold = W[i,j]+W[j,i] (bi<bj) else W[i,j].
// k >= 2304 -> concat (cps_w).
__device__ __attribute__((aligned(256))) unsigned short g_cpstU[(size_t)NSTG_T * STG];
__device__ __attribute__((aligned(256))) unsigned short g_cprtU[(size_t)NSTG_F * STG];
__device__ float g_smw[7 * 64];
__device__ float g_smb[7];
__device__ float g_biasC[64];   // cps_b + cpst_b
__device__ float g_biasF[64];   // cpr_b + cprt_b

// per-stage kron block params, packed: half0 bits[0:6], half1 bits[7:13]
#define KE(BI0,BJ0,R0,BI1,BJ1,R1) \
    ((BI0) | ((BJ0) << 3) | ((R0) << 6) | ((BI1) << 7) | ((BJ1) << 10) | ((R1) << 13))
__device__ __constant__ int g_ktab[18] = {
    KE(0,0,1, 0,1,1), KE(0,2,0, 0,3,0), KE(0,4,0, 0,5,0), KE(0,6,0, 0,7,0),
    KE(1,1,1, 1,2,1), KE(1,3,0, 1,4,0), KE(1,5,0, 1,6,0), KE(1,7,0, 2,2,1),
    KE(2,3,1, 2,4,0), KE(2,5,0, 2,6,0), KE(2,7,0, 3,3,1), KE(3,4,1, 3,5,0),
    KE(3,6,0, 3,7,0), KE(4,4,1, 4,5,1), KE(4,6,0, 4,7,0), KE(5,5,1, 5,6,1),
    KE(5,7,0, 6,6,1), KE(6,7,1, 7,7,1)
};

__device__ __forceinline__ float b2f(unsigned short u) {
    unsigned int x = ((unsigned int)u) << 16;
    return __builtin_bit_cast(float, x);
}
__device__ __forceinline__ unsigned short f2b(float f) {
    return __builtin_bit_cast(unsigned short, (__bf16)f);
}
__device__ __forceinline__ unsigned short f2h(float f) {
    return __builtin_bit_cast(unsigned short, (_Float16)f);
}
__device__ __forceinline__ float scrub(float v) {
    return fminf(fmaxf(v, -64.f), 64.f);
}
__device__ __forceinline__ float ldf(const void* p, size_t i, int isb) {
    return isb ? b2f(((const unsigned short*)p)[i]) : ((const float*)p)[i];
}
__device__ __forceinline__ int detect_isb(const void* voc_b) {
    const unsigned int* p = (const unsigned int*)voc_b;
    int ok = 1;
    for (int k = 0; k < 32; k++) {
        float v = b2f((unsigned short)(p[k] & 0xFFFFu));
        if (!(fabsf(v) <= 0.0502f)) ok = 0;
    }
    return ok;
}

// ---------- kernel: fused preprocessing ----------
__global__ __launch_bounds__(256) void k_prep(
    const void* voc_w, const void* voc_b,
    const void* cps_w, const void* cps_b, const void* cpst_w, const void* cpst_b,
    const void* cpr_w, const void* cpr_b, const void* cprt_w, const void* cprt_b,
    const void* sm_w, const void* sm_b)
{
    __shared__ float tile[64][65];
    __shared__ float vb[64];
    const int isb = detect_isb(voc_b);
    if (blockIdx.x < 512) {
        int gid = blockIdx.x * 256 + threadIdx.x;
        int stride = 512 * 256;
        // ---- g_cpstU: symmetric-folded kron (role-swapped slots) + concat ----
        for (int d = gid; d < 64 * W2T; d += stride) {
            int s    = d / STG;
            int rem  = d - s * STG;
            int kbl  = rem >> 11;
            int rem2 = rem & 2047;
            int nt   = rem2 >> 9;
            int rem3 = rem2 & 511;
            int q    = rem3 >> 7;
            int rem4 = rem3 & 127;
            int sub  = rem4 >> 3;
            int z    = rem4 & 7;
            int n    = nt * 16 + sub;
            int k    = s * 128 + kbl * 32 + q * 8 + z;
            float w;
            if (k < 2304) {
                int b   = k >> 6;
                int p2l = (k >> 5) & 1;
                int bi = 0, remb = b;
                while (remb >= 8 - bi) { remb -= 8 - bi; bi++; }
                int bj = bi + remb;
                int i = bi * 8 + z;               // A-vector index
                int j = bj * 8 + 2 * q + p2l;     // A-scalar index (pair-adjacent)
                w = ldf(cpst_w, (size_t)n * 4096 + i * 64 + j, isb);
                if (bi != bj)
                    w += ldf(cpst_w, (size_t)n * 4096 + j * 64 + i, isb);
            } else {
                w = ldf(cps_w, (size_t)n * 128 + (k - 2304), isb);
            }
            g_cpstU[d] = f2h(w);
        }
        // ---- g_cprtU: plain layout (33 stages) ----
        for (int d = gid; d < 64 * W2F; d += stride) {
            int s    = d / STG;
            int rem  = d - s * STG;
            int kbl  = rem >> 11;
            int rem2 = rem & 2047;
            int nt   = rem2 >> 9;
            int rem3 = rem2 & 511;
            int q    = rem3 >> 7;
            int rem4 = rem3 & 127;
            int sub  = rem4 >> 3;
            int z    = rem4 & 7;
            int n    = nt * 16 + sub;
            int k    = s * 128 + kbl * 32 + q * 8 + z;
            float v2 = (k < 4096) ? ldf(cprt_w, (size_t)n * 4096 + k, isb)
                                  : ldf(cpr_w,  (size_t)n * 128 + (k - 4096), isb);
            g_cprtU[d] = f2h(v2);
        }
        for (int i = gid; i < 448; i += stride) g_smw[i] = ldf(sm_w, i, isb);
        if (gid < 64) {
            g_biasC[gid] = ldf(cps_b, gid, isb) + ldf(cpst_b, gid, isb);
            g_biasF[gid] = ldf(cpr_b, gid, isb) + ldf(cprt_b, gid, isb);
        }
        if (gid < 7) g_smb[gid] = ldf(sm_b, gid, isb);
    } else {
        int t = threadIdx.x;
        if (t < 64) vb[t] = ldf(voc_b, t, isb);
        int v0 = (blockIdx.x - 512) * 64;
        int vl = t & 63, dr = t >> 6;
        #pragma unroll
        for (int i = 0; i < 16; i++) {
            int d = dr * 16 + i;
            int v = v0 + vl;
            tile[vl][d] = (v < VOC) ? ldf(voc_w, (size_t)d * VOC + v, isb) : 0.f;
        }
        __syncthreads();
        int dl = t & 63, vr0 = t >> 6;
        #pragma unroll
        for (int i = 0; i < 16; i++) {
            int vr = vr0 * 16 + i;
            int v = v0 + vr;
            if (v < VOC) g_vocT[(size_t)v * 64 + dl] = f2h(tile[vr][dl] + vb[dl]);
        }
    }
}

// epilogue for owned chunk CO (path A): add bias, tanh, store (f16)
#define EPILOGUE(CO)                                                          \
    {                                                                         \
        _Pragma("unroll")                                                     \
        for (int nt = 0; nt < 4; nt++) {                                      \
            int e = nt * 16 + sub;                                            \
            _Pragma("unroll")                                                 \
            for (int rr = 0; rr < 4; rr++) {                                  \
                int m = chv[CO] * 16 + q * 4 + rr;                            \
                if (m < nodes) {                                              \
                    int t2 = m >> lg, n2 = m & (cnew - 1);                    \
                    Xs[(t2 * 64 + n2) * XSTR + e] =                           \
                        f2h(tanhf(scrub(acc[CO][nt][rr] + biasC[e])));        \
                }                                                             \
            }                                                                 \
        }                                                                     \
    }

// pair exchange (path A): wave-indexed 8-slot scratch (receiver reads wave^1)
#define EXSEND(CS)                                                            \
    { _Pragma("unroll")                                                       \
      for (int nt = 0; nt < 4; nt++)                                          \
          *(f32x4*)(exchS + wave * 1024 + nt * 256 + lane * 4) = acc[CS][nt]; }

#define EXRECV(CO)                                                            \
    { _Pragma("unroll")                                                       \
      for (int nt = 0; nt < 4; nt++) {                                        \
          f32x4 v_ = *(const f32x4*)(exchS + (wave ^ 1) * 1024 + nt * 256 + lane * 4); \
          _Pragma("unroll")                                                   \
          for (int z = 0; z < 4; z++) acc[CO][nt][z] += v_[z];                \
      } }

// load this wave's 8 B-fragments of a stage from GLOBAL (L1/L2-resident)
#define BLD8(BF, SBASE)                                                       \
    { const unsigned short* gs_ = (SBASE) + half * 4096 + lane * 8;           \
      _Pragma("unroll")                                                       \
      for (int j = 0; j < 8; j++)                                             \
          BF[j] = *(const f16x8*)(gs_ + (j >> 2) * 2048 + (j & 3) * 512); }

#define KMM(CI, AV, B0, B1, B2, B3)                                           \
    { f16x8 a_ = (AV);                                                        \
      acc[CI][0] = __builtin_amdgcn_mfma_f32_16x16x32_f16(a_, B0, acc[CI][0], 0, 0, 0); \
      acc[CI][1] = __builtin_amdgcn_mfma_f32_16x16x32_f16(a_, B1, acc[CI][1], 0, 0, 0); \
      acc[CI][2] = __builtin_amdgcn_mfma_f32_16x16x32_f16(a_, B2, acc[CI][2], 0, 0, 0); \
      acc[CI][3] = __builtin_amdgcn_mfma_f32_16x16x32_f16(a_, B3, acc[CI][3], 0, 0, 0); }

#define KBLOCKR(BF, BI, BJ, RLD)                                              \
    if (act[0]) {                                                             \
        if (RLD) {                                                            \
            lA0 = *(const f16x8*)(Xs + slotL[0] + (BI) * 8);                  \
            if (act[1]) lA1 = *(const f16x8*)(Xs + slotL[1] + (BI) * 8);      \
            if (act[2]) lA2 = *(const f16x8*)(Xs + slotL[2] + (BI) * 8);      \
            if (act[3]) lA3 = *(const f16x8*)(Xs + slotL[3] + (BI) * 8);      \
        }                                                                     \
        _Float16 sc0[4], sc1[4];                                              \
        _Pragma("unroll")                                                     \
        for (int c = 0; c < 4; c++)                                           \
            if (act[c]) {                                                     \
                unsigned pr_ = *(const unsigned*)(Xs + slotL[c] + (BJ) * 8 + 2 * q); \
                sc0[c] = __builtin_bit_cast(_Float16, (unsigned short)(pr_ & 0xFFFFu)); \
                sc1[c] = __builtin_bit_cast(_Float16, (unsigned short)(pr_ >> 16));     \
            }                                                                 \
        _Pragma("unroll")                                                     \
        for (int p2 = 0; p2 < 2; p2++) {                                      \
            KMM(0, lA0 * (p2 ? sc1[0] : sc0[0]),                              \
                BF[p2 * 4 + 0], BF[p2 * 4 + 1], BF[p2 * 4 + 2], BF[p2 * 4 + 3]) \
            if (act[1]) KMM(1, lA1 * (p2 ? sc1[1] : sc0[1]),                  \
                BF[p2 * 4 + 0], BF[p2 * 4 + 1], BF[p2 * 4 + 2], BF[p2 * 4 + 3]) \
            if (act[2]) KMM(2, lA2 * (p2 ? sc1[2] : sc0[2]),                  \
                BF[p2 * 4 + 0], BF[p2 * 4 + 1], BF[p2 * 4 + 2], BF[p2 * 4 + 3]) \
            if (act[3]) KMM(3, lA3 * (p2 ? sc1[3] : sc0[3]),                  \
                BF[p2 * 4 + 0], BF[p2 * 4 + 1], BF[p2 * 4 + 2], BF[p2 * 4 + 3]) \
        }                                                                     \
    }

#define KRUNR(S, BF)                                                          \
    {                                                                         \
        int e_   = g_ktab[S];                                                 \
        int ent_ = half ? (e_ >> 7) : e_;                                     \
        int bi_  = ent_ & 7;                                                  \
        int bj_  = (ent_ >> 3) & 7;                                           \
        int rld_ = (ent_ >> 6) & 1;                                           \
        KBLOCKR((BF), bi_, bj_, rld_)                                         \
    }

// ---- deep-level (N-split) helpers: single chunk, ntn N-tiles per wave ----
#define DBLD2(BF, SBASE)                                                      \
    { const unsigned short* gs_ = (SBASE) + half * 4096 + lane * 8;           \
      BF[0] = *(const f16x8*)(gs_ + (ntb + 0) * 512);                         \
      BF[1] = *(const f16x8*)(gs_ + (ntb + 1) * 512);                         \
      BF[2] = *(const f16x8*)(gs_ + 2048 + (ntb + 0) * 512);                  \
      BF[3] = *(const f16x8*)(gs_ + 2048 + (ntb + 1) * 512); }

#define DBLD1(BF, SBASE)                                                      \
    { const unsigned short* gs_ = (SBASE) + half * 4096 + ntb * 512 + lane * 8; \
      BF[0] = *(const f16x8*)(gs_);                                           \
      BF[1] = *(const f16x8*)(gs_ + 2048); }

#define DKRUN2(S, BF)                                                         \
    {                                                                         \
        int e_   = g_ktab[S];                                                 \
        int ent_ = half ? (e_ >> 7) : e_;                                     \
        int bi_  = ent_ & 7;                                                  \
        int bj_  = (ent_ >> 3) & 7;                                           \
        if ((ent_ >> 6) & 1) lAD = *(const f16x8*)(Xs + slotD + bi_ * 8);     \
        unsigned pr_ = *(const unsigned*)(Xs + slotD + bj_ * 8 + 2 * q);      \
        _Float16 s0_ = __builtin_bit_cast(_Float16, (unsigned short)(pr_ & 0xFFFFu)); \
        _Float16 s1_ = __builtin_bit_cast(_Float16, (unsigned short)(pr_ >> 16));     \
        f16x8 a0_ = lAD * s0_;                                                \
        accD0 = __builtin_amdgcn_mfma_f32_16x16x32_f16(a0_, BF[0], accD0, 0, 0, 0); \
        accD1 = __builtin_amdgcn_mfma_f32_16x16x32_f16(a0_, BF[1], accD1, 0, 0, 0); \
        f16x8 a1_ = lAD * s1_;                                                \
        accD0 = __builtin_amdgcn_mfma_f32_16x16x32_f16(a1_, BF[2], accD0, 0, 0, 0); \
        accD1 = __builtin_amdgcn_mfma_f32_16x16x32_f16(a1_, BF[3], accD1, 0, 0, 0); \
    }

#define DKRUN1(S, BF)                                                         \
    {                                                                         \
        int e_   = g_ktab[S];                                                 \
        int ent_ = half ? (e_ >> 7) : e_;                                     \
        int bi_  = ent_ & 7;                                                  \
        int bj_  = (ent_ >> 3) & 7;                                           \
        if ((ent_ >> 6) & 1) lAD = *(const f16x8*)(Xs + slotD + bi_ * 8);     \
        unsigned pr_ = *(const unsigned*)(Xs + slotD + bj_ * 8 + 2 * q);      \
        _Float16 s0_ = __builtin_bit_cast(_Float16, (unsigned short)(pr_ & 0xFFFFu)); \
        _Float16 s1_ = __builtin_bit_cast(_Float16, (unsigned short)(pr_ >> 16));     \
        accD0 = __builtin_amdgcn_mfma_f32_16x16x32_f16(lAD * s0_, BF[0], accD0, 0, 0, 0); \
        accD0 = __builtin_amdgcn_mfma_f32_16x16x32_f16(lAD * s1_, BF[1], accD0, 0, 0, 0); \
    }

// ---------- kernel: full tree composition ----------
// 512 thr = 8 waves = 4 pairs, 1 WG/CU.  Barrier-free register-B streaming
// (round 13).  SHALLOW levels (nchunks>=4): spread chunks ch = p + 4c, path A.
// DEEP levels (nchunks<=2): N-SPLIT across pairs -- every pair works on chunk
// p/ppc with N-tiles [ntb, ntb+ntn): lv3 2 pairs/chunk x 2 tiles, lv4/5
// 4 pairs x 1 tile.  All 8 waves stay live at every level (round-11 lesson:
// parked waves = exposed latency), per-wave deep work shrinks 2-4x.
// N-split is sync-free (disjoint output columns); one pair-exchange round
// (K halves) finishes each deep level.
// LDS: Xs 73728 + exchS 32768 + biasC 256 = 106752 B.
__global__ __launch_bounds__(512, 2)
void k_tree(const int* __restrict__ lleaf, const int* __restrict__ rleaf)
{
    __shared__ __attribute__((aligned(16))) unsigned short Xs[512 * XSTR];   // 73728 B
    __shared__ __attribute__((aligned(16))) float exchS[8192];               // 32768 B
    __shared__ float biasC[64];
    const int tid = threadIdx.x;
    const int wg  = blockIdx.x;

    if (tid < 64) biasC[tid] = g_biasC[tid];

    // ---- leaf gather: row tid = (tree tid>>6, leaf tid&63) ----
    {
        int t = tid >> 6, i = tid & 63;
        int gidx = wg * TPW + t;                 // 0..1023 left, 1024..2047 right
        int b = (gidx < 1024) ? gidx : gidx - 1024;
        const int* lv2 = (gidx < 1024) ? lleaf : rleaf;
        int idx = lv2[b * 64 + i];
        idx = (idx < 0) ? 0 : ((idx >= VOC) ? VOC - 1 : idx);
        const uint4* src = (const uint4*)(g_vocT + (size_t)idx * 64);
        uint4* dst = (uint4*)(Xs + tid * XSTR);
        #pragma unroll
        for (int z = 0; z < 8; z++) dst[z] = src[z];
    }

    __syncthreads();   // Xs + biasC ready

    const int lane = tid & 63, wave = tid >> 6;
    const int q = lane >> 4, sub = lane & 15;
    const int p = wave >> 1, half = wave & 1;

    #pragma unroll 1
    for (int lv = 0; lv < 6; lv++) {
        const int lg = 5 - lv;
        const int cnew = 1 << lg;
        const int nodes = TPW << lg;             // 256,128,64,32,16,8
        const int nchunks = (nodes + 15) >> 4;   // 16,8,4,2,1,1

        if (nchunks >= 4) {
            // =============== PATH A: spread chunks, full N ===============
            int act[4], chv[4], slotL[4];
            #pragma unroll
            for (int c = 0; c < 4; c++) {
                int ch = p + 4 * c;
                act[c] = (ch < nchunks);
                chv[c] = ch;
                int m = ch * 16 + sub;
                if (!act[c] || m >= nodes) m = 0;
                int t = m >> lg, n = m & (cnew - 1);
                slotL[c] = (t * 64 + 2 * n) * XSTR;
            }

            f16x8 lA0 = {}, lA1 = {}, lA2 = {}, lA3 = {};
            f32x4 acc[4][4];
            #pragma unroll
            for (int c = 0; c < 4; c++)
                #pragma unroll
                for (int nt = 0; nt < 4; nt++)
                    #pragma unroll
                    for (int z = 0; z < 4; z++) acc[c][nt][z] = 0.f;

            f16x8 bfA[8], bfB[8];
            if (act[0]) BLD8(bfA, g_cpstU)
            #pragma unroll 1
            for (int t = 0; t < 9; t++) {
                if (act[0]) BLD8(bfB, g_cpstU + (size_t)(2 * t + 1) * STG)
                KRUNR(2 * t, bfA)
                if (act[0]) BLD8(bfA, g_cpstU + (size_t)(2 * t + 2) * STG)
                KRUNR(2 * t + 1, bfB)
            }
            if (act[0]) {                        // concat (bfA = stage 18)
                #pragma unroll
                for (int p2 = 0; p2 < 2; p2++) {
                    #pragma unroll
                    for (int c = 0; c < 4; c++) {
                        if (!act[c]) continue;
                        f16x8 A = *(const f16x8*)(Xs + slotL[c] + half * XSTR + p2 * 32 + q * 8);
                        acc[c][0] = __builtin_amdgcn_mfma_f32_16x16x32_f16(A, bfA[p2 * 4 + 0], acc[c][0], 0, 0, 0);
                        acc[c][1] = __builtin_amdgcn_mfma_f32_16x16x32_f16(A, bfA[p2 * 4 + 1], acc[c][1], 0, 0, 0);
                        acc[c][2] = __builtin_amdgcn_mfma_f32_16x16x32_f16(A, bfA[p2 * 4 + 2], acc[c][2], 0, 0, 0);
                        acc[c][3] = __builtin_amdgcn_mfma_f32_16x16x32_f16(A, bfA[p2 * 4 + 3], acc[c][3], 0, 0, 0);
                    }
                }
            }

            // pair exchange + epilogue (first barrier also orders Xs reads)
            if (half == 0) { if (act[1]) EXSEND(1) } else { if (act[0]) EXSEND(0) }
            __syncthreads();
            if (half == 0) {
                if (act[0]) { EXRECV(0) EPILOGUE(0) }
            } else {
                if (act[1]) { EXRECV(1) EPILOGUE(1) }
            }
            __syncthreads();
            if (half == 0) { if (act[3]) EXSEND(3) } else { if (act[2]) EXSEND(2) }
            __syncthreads();
            if (half == 0) {
                if (act[2]) { EXRECV(2) EPILOGUE(2) }
            } else {
                if (act[3]) { EXRECV(3) EPILOGUE(3) }
            }
            __syncthreads();
        } else if (nchunks == 2) {
            // =============== PATH B (lv3): 2 pairs/chunk, 2 N-tiles/wave ===============
            const int chD = p >> 1;
            const int ntb = (p & 1) * 2;
            int mD = chD * 16 + sub;             // < 32 = nodes, always valid
            int tD = mD >> lg, nD = mD & (cnew - 1);
            const int slotD = (tD * 64 + 2 * nD) * XSTR;
            f16x8 lAD = {};
            f32x4 accD0 = {0.f,0.f,0.f,0.f}, accD1 = {0.f,0.f,0.f,0.f};

            f16x8 dA[4], dB[4];
            DBLD2(dA, g_cpstU)
            #pragma unroll 1
            for (int t = 0; t < 9; t++) {
                DBLD2(dB, g_cpstU + (size_t)(2 * t + 1) * STG)
                DKRUN2(2 * t, dA)
                DBLD2(dA, g_cpstU + (size_t)(2 * t + 2) * STG)   // t=8 -> concat
                DKRUN2(2 * t + 1, dB)
            }
            {   // concat (dA = stage 18 fragments for this wave's nts)
                #pragma unroll
                for (int p2 = 0; p2 < 2; p2++) {
                    f16x8 A = *(const f16x8*)(Xs + slotD + half * XSTR + p2 * 32 + q * 8);
                    accD0 = __builtin_amdgcn_mfma_f32_16x16x32_f16(A, dA[p2 * 2 + 0], accD0, 0, 0, 0);
                    accD1 = __builtin_amdgcn_mfma_f32_16x16x32_f16(A, dA[p2 * 2 + 1], accD1, 0, 0, 0);
                }
            }
            // exchange: half1 sends, half0 receives + epilogue
            if (half == 1) {
                *(f32x4*)(exchS + p * 1024 + lane * 4) = accD0;
                *(f32x4*)(exchS + p * 1024 + 256 + lane * 4) = accD1;
            }
            __syncthreads();
            if (half == 0) {
                {   f32x4 v0 = *(const f32x4*)(exchS + p * 1024 + lane * 4);
                    f32x4 v1 = *(const f32x4*)(exchS + p * 1024 + 256 + lane * 4);
                    #pragma unroll
                    for (int z = 0; z < 4; z++) { accD0[z] += v0[z]; accD1[z] += v1[z]; }
                }
                #pragma unroll
                for (int j = 0; j < 2; j++) {
                    int e = (ntb + j) * 16 + sub;
                    #pragma unroll
                    for (int rr = 0; rr < 4; rr++) {
                        int m = chD * 16 + q * 4 + rr;
                        int t2 = m >> lg, n2 = m & (cnew - 1);
                        float av = j ? accD1[rr] : accD0[rr];
                        Xs[(t2 * 64 + n2) * XSTR + e] = f2h(tanhf(scrub(av + biasC[e])));
                    }
                }
            }
            __syncthreads();
        } else {
            // =============== PATH C (lv4/5): 4 pairs on 1 chunk, 1 N-tile/wave ===============
            const int ntb = p;
            int mD = sub;
            if (mD >= nodes) mD = 0;             // lv5: rows 8..15 dummy
            int tD = mD >> lg, nD = mD & (cnew - 1);
            const int slotD = (tD * 64 + 2 * nD) * XSTR;
            f16x8 lAD = {};
            f32x4 accD0 = {0.f,0.f,0.f,0.f};

            f16x8 dA[2], dB[2];
            DBLD1(dA, g_cpstU)
            #pragma unroll 1
            for (int t = 0; t < 9; t++) {
                DBLD1(dB, g_cpstU + (size_t)(2 * t + 1) * STG)
                DKRUN1(2 * t, dA)
                DBLD1(dA, g_cpstU + (size_t)(2 * t + 2) * STG)   // t=8 -> concat
                DKRUN1(2 * t + 1, dB)
            }
            {   // concat
                #pragma unroll
                for (int p2 = 0; p2 < 2; p2++) {
                    f16x8 A = *(const f16x8*)(Xs + slotD + half * XSTR + p2 * 32 + q * 8);
                    accD0 = __builtin_amdgcn_mfma_f32_16x16x32_f16(A, dA[p2], accD0, 0, 0, 0);
                }
            }
            if (half == 1)
                *(f32x4*)(exchS + p * 1024 + lane * 4) = accD0;
            __syncthreads();
            if (half == 0) {
                {   f32x4 v0 = *(const f32x4*)(exchS + p * 1024 + lane * 4);
                    #pragma unroll
                    for (int z = 0; z < 4; z++) accD0[z] += v0[z];
                }
                int e = ntb * 16 + sub;
                if (lv < 5) {
                    #pragma unroll
                    for (int rr = 0; rr < 4; rr++) {
                        int m = q * 4 + rr;                      // < 16 = nodes
                        int t2 = m >> lg, n2 = m & (cnew - 1);
                        Xs[(t2 * 64 + n2) * XSTR + e] = f2h(tanhf(scrub(accD0[rr] + biasC[e])));
                    }
                } else {
                    #pragma unroll
                    for (int rr = 0; rr < 4; rr++) {
                        int m = q * 4 + rr;                      // tree index
                        if (m < TPW)
                            g_roots[((size_t)wg * TPW + m) * 64 + e] =
                                f2h(tanhf(scrub(accD0[rr] + biasC[e])));
                    }
                }
            }
            __syncthreads();
        }
    }
}

// ---- k_final: load wave w's 4 B-fragments of stage S from GLOBAL ----
#define BLD4(BF, S)                                                           \
    { const unsigned short* gs_ = g_cprtU + (size_t)(S) * STG + w * 512 + lane * 8; \
      _Pragma("unroll")                                                       \
      for (int j = 0; j < 4; j++)                                             \
          BF[j] = *(const f16x8*)(gs_ + j * 2048); }

// kron stage S of k_final from register buffer BF
#define FKRONR(S, BF)                                                         \
    { _Pragma("unroll")                                                       \
      for (int ii = 0; ii < 2; ii++) {                                        \
          int i_ = 2 * (S) + ii;                                              \
          _Float16 li_ = __builtin_bit_cast(_Float16, Lv[rowLo + i_]);        \
          _Pragma("unroll")                                                   \
          for (int p2 = 0; p2 < 2; p2++) {                                    \
              f16x8 afr_ = Ra[p2] * li_;                                      \
              acc = __builtin_amdgcn_mfma_f32_16x16x32_f16(afr_, BF[2 * ii + p2], acc, 0, 0, 0); \
          }                                                                   \
      } }

// ---------- kernel: final cpr/cprt + leaky_relu + softmax ----------
// 64 WGs x 16 items, 4 waves; wave w owns N-tile w (fragments DISJOINT per
// wave -> zero read amplification).  B loaded global->register ping-pong,
// ZERO barriers in the 33-stage loop (weights L2-resident, ~528KB).
__global__ __launch_bounds__(256, 2) void k_final(const void* __restrict__ voc_b,
                                                  void* __restrict__ out)
{
    __shared__ __attribute__((aligned(16))) unsigned short Lv[IPW * XSTR], Rv[IPW * XSTR];
    __shared__ float actS[IPW][65];
    __shared__ float smw[7][64];
    __shared__ float smbS[7];
    __shared__ float biasF[64];
    const int tid = threadIdx.x, wg = blockIdx.x;
    const int isb = detect_isb(voc_b);

    if (tid < 64) biasF[tid] = g_biasF[tid];
    if (tid < 7)  smbS[tid] = g_smb[tid];
    for (int z = tid; z < 448; z += 256) smw[z >> 6][z & 63] = g_smw[z];

    {   // stage l and r roots for this WG's 16 items: 256 threads x 1 uint4
        int side = tid >> 7, idx = tid & 127;
        int item = idx >> 3, piece = idx & 7;
        const uint4* s4 = (const uint4*)(g_roots +
            ((size_t)(side * 1024) + (size_t)wg * IPW + item) * 64 + piece * 8);
        uint4* d4 = (uint4*)((side ? Rv : Lv) + item * XSTR + piece * 8);
        *d4 = *s4;
    }

    const int lane = tid & 63, w = tid >> 6;
    const int q = lane >> 4, sub = lane & 15;
    const int rowLo = sub * XSTR;                // item = sub (A-operand rows)

    f16x8 bA[4], bB[4];
    BLD4(bA, 0)                                  // global, independent of LDS

    __syncthreads();   // roots + smem ready

    f16x8 Ra[2];                                 // kron = l[i] * r[j]
    Ra[0] = *(const f16x8*)(Rv + rowLo + q * 8);
    Ra[1] = *(const f16x8*)(Rv + rowLo + 32 + q * 8);

    f32x4 acc;
    #pragma unroll
    for (int z = 0; z < 4; z++) acc[z] = 0.f;

    #pragma unroll 1
    for (int t = 0; t < 16; t++) {               // kron stages 0..31
        BLD4(bB, 2 * t + 1)
        FKRONR(2 * t, bA)
        BLD4(bA, 2 * t + 2)                      // t=15 -> stage 32 (concat)
        FKRONR(2 * t + 1, bB)
    }

    // ---- concat stage (bA holds stage-32 fragments, kbl = j) ----
    {
        f16x8 A4[4];
        A4[0] = *(const f16x8*)(Lv + rowLo + q * 8);
        A4[1] = *(const f16x8*)(Lv + rowLo + 32 + q * 8);
        A4[2] = *(const f16x8*)(Rv + rowLo + q * 8);
        A4[3] = *(const f16x8*)(Rv + rowLo + 32 + q * 8);
        #pragma unroll
        for (int kbl = 0; kbl < 4; kbl++)
            acc = __builtin_amdgcn_mfma_f32_16x16x32_f16(A4[kbl], bA[kbl], acc, 0, 0, 0);
    }

    // epilogue: bias + leaky_relu -> LDS  (actS disjoint from Lv/Rv)
    {
        int e = w * 16 + sub;
        #pragma unroll
        for (int rr = 0; rr < 4; rr++) {
            int item = q * 4 + rr;
            float v = scrub(acc[rr] + biasF[e]);
            v = (v > 0.f) ? v : 0.01f * v;
            actS[item][e] = v;
        }
    }
    __syncthreads();

    if (tid < IPW) {
        float lg[7];
        #pragma unroll
        for (int j = 0; j < 7; j++) lg[j] = smbS[j];
        for (int e = 0; e < 64; e++) {
            float a = actS[tid][e];
            #pragma unroll
            for (int j = 0; j < 7; j++) lg[j] += smw[j][e] * a;
        }
        float mx = lg[0];
        #pragma unroll
        for (int j = 1; j < 7; j++) mx = fmaxf(mx, lg[j]);
        float s = 0.f, pr[7];
        #pragma unroll
        for (int j = 0; j < 7; j++) { pr[j] = expf(lg[j] - mx); s += pr[j]; }
        float inv = 1.f / s;
        size_t b = (size_t)wg * IPW + tid;
        if (isb) {
            unsigned short* o = (unsigned short*)out;
            #pragma unroll
            for (int j = 0; j < 7; j++) o[b * 7 + j] = f2b(pr[j] * inv);
        } else {
            float* o = (float*)out;
            #pragma unroll
            for (int j = 0; j < 7; j++) o[b * 7 + j] = pr[j] * inv;
        }
    }
}

// ---------- host launcher ----------
extern "C" void kernel_launch(void* const* d_in, const int* in_sizes, int n_in,
                              void* d_out, int out_size, void* d_ws, size_t ws_size,
                              hipStream_t stream) {
    const int* lleaf = (const int*)d_in[0];
    const int* rleaf = (const int*)d_in[1];
    const void* voc_w  = d_in[2];
    const void* voc_b  = d_in[3];
    const void* cps_w  = d_in[4];
    const void* cps_b  = d_in[5];
    const void* cpst_w = d_in[6];
    const void* cpst_b = d_in[7];
    const void* cpr_w  = d_in[8];
    const void* cpr_b  = d_in[9];
    const void* cprt_w = d_in[10];
    const void* cprt_b = d_in[11];
    const void* sm_w   = d_in[12];
    const void* sm_b   = d_in[13];

    k_prep<<<512 + (VOC + 63) / 64, 256, 0, stream>>>(
        voc_w, voc_b, cps_w, cps_b, cpst_w, cpst_b,
        cpr_w, cpr_b, cprt_w, cprt_b, sm_w, sm_b);
    k_tree<<<2048 / TPW, 512, 0, stream>>>(lleaf, rleaf);
    k_final<<<64, 256, 0, stream>>>(voc_b, (unsigned short*)d_out);
}